// Round 10
// baseline (977.005 us; speedup 1.0000x reference)
//
#include <hip/hip_runtime.h>
#include <hip/hip_fp16.h>

#define NNODES 500000
#define HID 8
#define BIN_SHIFT 9
#define BINW 512               // nodes per bin
#define NBIN 977               // ceil(500000/512)
#define SCAN_BLK 1024
#define SGRID 256              // binscatter blocks (1/CU)
#define CAP 24                 // LDS bucket capacity per bin
#define BUFCAP 18432           // binsort staging cap (mean 16384, +16 sigma)
#define GSZ 16                 // lanes cooperating per dst node in agg passes

typedef int intx4 __attribute__((ext_vector_type(4)));

__device__ __forceinline__ unsigned int packh2(float a, float b) {
    __half2 h = __floats2half2_rn(a, b);
    return *reinterpret_cast<unsigned int*>(&h);
}
__device__ __forceinline__ float2 unpackh2(unsigned int u) {
    __half2 h = *reinterpret_cast<__half2*>(&u);
    return __half22float2(h);
}
__device__ __forceinline__ float elu(float t) { return t > 0.0f ? t : expm1f(t); }
__device__ __forceinline__ int nt_load_i(const int* p) { return __builtin_nontemporal_load(p); }
__device__ __forceinline__ intx4 nt_load_i4(const intx4* p) { return __builtin_nontemporal_load(p); }

// software e4m3 encode (RNE)
__device__ __forceinline__ unsigned int enc_e4m3(float x) {
    unsigned sgn = (__float_as_uint(x) >> 31) << 7;
    float ax = fabsf(x);
    if (ax >= 448.f) return sgn | 0x7E;
    if (ax < 0.015625f) {
        unsigned q = (unsigned)__float2int_rn(ax * 512.0f);
        return sgn | q;
    }
    unsigned u = __float_as_uint(ax);
    int te = (int)((u >> 23) & 0xFF) - 120;
    unsigned m = u & 0x7FFFFF;
    unsigned r = (m + 0x7FFFF + ((m >> 20) & 1)) >> 20;
    unsigned code = ((unsigned)te << 3) + r;
    if (code > 0x7E) code = 0x7E;
    return sgn | code;
}

// VALU e4m3 decode, 2 bytes -> float2, exact (no LUT, no LDS)
__device__ __forceinline__ float2 dec2_e4m3(unsigned int b01) {
    unsigned int x = (b01 & 0xFFu) | ((b01 & 0xFF00u) << 8);
    unsigned int h = ((x & 0x00800080u) << 8) | ((x & 0x007F007Fu) << 7);
    __half2 hv = *reinterpret_cast<__half2*>(&h);
    const __half2 s256 = __floats2half2_rn(256.0f, 256.0f);
    hv = __hmul2(hv, s256);
    return __half22float2(hv);
}

// ================= CSR build =================
__global__ void binhist_kernel(const int* __restrict__ dst, int E, int* __restrict__ gbinhist) {
    __shared__ int hist[NBIN];
    for (int b = threadIdx.x; b < NBIN; b += blockDim.x) hist[b] = 0;
    __syncthreads();
    int stride = gridDim.x * blockDim.x;
    const intx4* d4 = (const intx4*)dst;
    int n4 = E >> 2;
    for (int e = blockIdx.x * blockDim.x + threadIdx.x; e < n4; e += stride) {
        intx4 d = nt_load_i4(&d4[e]);
        atomicAdd(&hist[d.x >> BIN_SHIFT], 1);
        atomicAdd(&hist[d.y >> BIN_SHIFT], 1);
        atomicAdd(&hist[d.z >> BIN_SHIFT], 1);
        atomicAdd(&hist[d.w >> BIN_SHIFT], 1);
    }
    int tail0 = n4 << 2;
    for (int e = tail0 + blockIdx.x * blockDim.x + threadIdx.x; e < E; e += stride)
        atomicAdd(&hist[dst[e] >> BIN_SHIFT], 1);
    __syncthreads();
    for (int b = threadIdx.x; b < NBIN; b += blockDim.x) {
        int c = hist[b];
        if (c) atomicAdd(&gbinhist[b], c);
    }
}

__global__ void scan1_kernel(const int* __restrict__ deg, int* __restrict__ excl,
                             int* __restrict__ bsum, int N) {
    __shared__ int sm[SCAN_BLK];
    int tid = threadIdx.x;
    int gid = blockIdx.x * SCAN_BLK + tid;
    int v = (gid < N) ? deg[gid] : 0;
    int x = v;
    sm[tid] = x;
    __syncthreads();
    for (int off = 1; off < SCAN_BLK; off <<= 1) {
        int t = (tid >= off) ? sm[tid - off] : 0;
        __syncthreads();
        x += t;
        sm[tid] = x;
        __syncthreads();
    }
    if (gid < N) excl[gid] = x - v;
    if (tid == SCAN_BLK - 1) bsum[blockIdx.x] = x;
}

__global__ void scan2_kernel(int* __restrict__ bsum, int nb) {
    __shared__ int sm[SCAN_BLK];
    int tid = threadIdx.x;
    int v = (tid < nb) ? bsum[tid] : 0;
    int x = v;
    sm[tid] = x;
    __syncthreads();
    for (int off = 1; off < SCAN_BLK; off <<= 1) {
        int t = (tid >= off) ? sm[tid - off] : 0;
        __syncthreads();
        x += t;
        sm[tid] = x;
        __syncthreads();
    }
    if (tid < nb) bsum[tid] = x - v;
}

__global__ void scan3b_kernel(const int* __restrict__ binexcl, const int* __restrict__ bsum,
                              int* __restrict__ ptr_bins, int* __restrict__ gcursor, int E) {
    int i = blockIdx.x * blockDim.x + threadIdx.x;
    if (i < NBIN) {
        int p = binexcl[i] + bsum[i / SCAN_BLK];
        ptr_bins[i] = p;
        gcursor[i] = p;
    }
    if (i == 0) ptr_bins[NBIN] = E;
}

// LDS-coalesced scatter: deposit into per-bin buckets; flush 16-word (64B) groups
__global__ void __launch_bounds__(1024) binscatter_kernel(
        const int* __restrict__ src, const int* __restrict__ dst,
        int E, int* __restrict__ gcursor, int* __restrict__ packed) {
    __shared__ int cnt[NBIN];
    __shared__ int bucket[NBIN][CAP];
    __shared__ int fq_bin[NBIN];
    __shared__ int fq_pos[NBIN];
    __shared__ int fq_n;
    int tid = threadIdx.x;
    int slice = (E + SGRID - 1) / SGRID;
    int e0 = blockIdx.x * slice;
    int e1 = min(E, e0 + slice);
    if (e0 >= e1) return;
    for (int b = tid; b < NBIN; b += 1024) cnt[b] = 0;
    if (tid == 0) fq_n = 0;
    __syncthreads();
    for (int base = e0; base < e1; base += 1024) {
        int e = base + tid;
        if (e < e1) {
            int d = nt_load_i(&dst[e]);
            int s = nt_load_i(&src[e]);
            int b = d >> BIN_SHIFT;
            int val = (s << BIN_SHIFT) | (d & (BINW - 1));
            int slot = atomicAdd(&cnt[b], 1);
            if (slot < CAP) bucket[b][slot] = val;
            else {
                int gp = atomicAdd(&gcursor[b], 1);
                packed[gp] = val;
            }
        }
        __syncthreads();
        if (tid < NBIN) {
            int c = min(cnt[tid], CAP);
            if (c >= 16) {
                int idx = atomicAdd(&fq_n, 1);
                fq_bin[idx] = tid;
                fq_pos[idx] = atomicAdd(&gcursor[tid], 16);
            }
        }
        __syncthreads();
        int nf = fq_n;
        for (int w = tid; w < nf * 16; w += 1024) {
            int q = w >> 4, j = w & 15;
            packed[fq_pos[q] + j] = bucket[fq_bin[q]][j];
        }
        __syncthreads();
        if (tid < NBIN) {
            int c = min(cnt[tid], CAP);
            if (c >= 16) {
                int rem = c - 16;
                for (int j = 0; j < rem; ++j) bucket[tid][j] = bucket[tid][16 + j];
                cnt[tid] = rem;
            } else {
                cnt[tid] = c;
            }
        }
        if (tid == 0) fq_n = 0;
        __syncthreads();
    }
    if (tid < NBIN) {
        int c = min(cnt[tid], CAP);
        if (c > 0) {
            int pos = atomicAdd(&gcursor[tid], c);
            for (int j = 0; j < c; ++j) packed[pos + j] = bucket[tid][j];
        }
    }
}

// per-bin LDS sort (512-node bins) -> final ssrc (in place), ptr, t1 (= dinv*x fp16x2)
__global__ void __launch_bounds__(512) binsort_kernel(
        const int* __restrict__ ptr_bins, int* __restrict__ ssrc,
        int* __restrict__ ptr, const float* __restrict__ x,
        unsigned int* __restrict__ t1, int N, int E) {
    __shared__ int buf[BUFCAP];
    __shared__ int hist[BINW];
    __shared__ int scn[BINW];
    __shared__ int cursor[BINW];
    int bin = blockIdx.x;
    int tid = threadIdx.x;
    int base = ptr_bins[bin];
    int len = min(ptr_bins[bin + 1] - base, BUFCAP);
    int node_base = bin << BIN_SHIFT;
    int nn = min(BINW, N - node_base);
    hist[tid] = 0;
    __syncthreads();
    for (int k = tid; k < len; k += 512) {
        int v = nt_load_i(&ssrc[base + k]);
        buf[k] = v;
        atomicAdd(&hist[v & (BINW - 1)], 1);
    }
    __syncthreads();
    int orig = hist[tid];
    int x_ = orig;
    scn[tid] = x_;
    __syncthreads();
    for (int off = 1; off < BINW; off <<= 1) {
        int t = (tid >= off) ? scn[tid - off] : 0;
        __syncthreads();
        x_ += t;
        scn[tid] = x_;
        __syncthreads();
    }
    if (tid < nn) {
        int ex = x_ - orig;
        int node = node_base + tid;
        ptr[node] = base + ex;
        cursor[tid] = ex;
        float dv = rsqrtf((float)orig + 1.0f);  // self-loop => deg+1
        float2 xv = *reinterpret_cast<const float2*>(x + 2 * (size_t)node);
        t1[node] = packh2(dv * xv.x, dv * xv.y);
    }
    if (bin == NBIN - 1 && tid == 0) ptr[N] = E;
    __syncthreads();
    for (int k = tid; k < len; k += 512) {
        int v = buf[k];
        int pos = atomicAdd(&cursor[v & (BINW - 1)], 1);
        ssrc[base + pos] = v >> BIN_SHIFT;
    }
}

// ========== layer pipeline: 3 gather passes, 16 lanes cooperate per dst ==========
// layer1: 2ch fp16 table (2MB). Butterfly-reduce; per-channel epilogue W1->elu->W2 -> t2
__global__ void __launch_bounds__(256) agg1_kernel(
        const unsigned int* __restrict__ t1, const int* __restrict__ ptr,
        const int* __restrict__ ssrc, const float* __restrict__ W1,
        const float* __restrict__ b1, const float* __restrict__ W2,
        uint2* __restrict__ t2, int N) {
    int g = blockIdx.x * (256 / GSZ) + (threadIdx.x >> 4);
    int lane = threadIdx.x & (GSZ - 1);
    if (g >= N) return;
    int e0 = ptr[g], e1 = ptr[g + 1];
    float sx = 0.f, sy = 0.f;
    for (int k = e0 + lane; k < e1; k += GSZ) {
        float2 p = unpackh2(t1[nt_load_i(&ssrc[k])]);
        sx += p.x; sy += p.y;
    }
    if (lane == 0) {  // self-loop
        float2 p = unpackh2(t1[g]);
        sx += p.x; sy += p.y;
    }
#pragma unroll
    for (int off = 1; off < GSZ; off <<= 1) {
        sx += __shfl_xor(sx, off, GSZ);
        sy += __shfl_xor(sy, off, GSZ);
    }
    float dv = rsqrtf((float)(e1 - e0) + 1.0f);
    int c = lane & 7;
    float h = elu(dv * (sx * W1[c] + sy * W1[HID + c]) + b1[c]);
    float acc = 0.f;
#pragma unroll
    for (int k = 0; k < HID; ++k)
        acc = fmaf(__shfl(h, k, GSZ), W2[k * HID + c], acc);
    unsigned int part = enc_e4m3(dv * acc) << ((c & 3) * 8);
    part |= __shfl_xor(part, 1, GSZ);
    part |= __shfl_xor(part, 2, GSZ);
    unsigned int hiw = __shfl(part, 4, GSZ);
    if (lane == 0) {
        __builtin_nontemporal_store(part, &t2[g].x);
        __builtin_nontemporal_store(hiw, &t2[g].y);
    }
}

// layer2: 8ch fp8 table (4MB). Butterfly-reduce 8ch; epilogue b2->elu->W3 -> t3
__global__ void __launch_bounds__(256) agg2_kernel(
        const uint2* __restrict__ tab, const int* __restrict__ ptr,
        const int* __restrict__ ssrc, const float* __restrict__ b2,
        const float* __restrict__ W3, uint2* __restrict__ t3, int N) {
    int g = blockIdx.x * (256 / GSZ) + (threadIdx.x >> 4);
    int lane = threadIdx.x & (GSZ - 1);
    if (g >= N) return;
    int e0 = ptr[g], e1 = ptr[g + 1];
    float s0 = 0.f, s1 = 0.f, s2 = 0.f, s3 = 0.f, s4 = 0.f, s5 = 0.f, s6 = 0.f, s7 = 0.f;
    for (int k = e0 + lane; k < e1; k += GSZ) {
        uint2 w = tab[nt_load_i(&ssrc[k])];
        float2 q0 = dec2_e4m3(w.x), q1 = dec2_e4m3(w.x >> 16);
        float2 q2 = dec2_e4m3(w.y), q3 = dec2_e4m3(w.y >> 16);
        s0 += q0.x; s1 += q0.y; s2 += q1.x; s3 += q1.y;
        s4 += q2.x; s5 += q2.y; s6 += q3.x; s7 += q3.y;
    }
    if (lane == 0) {  // self-loop
        uint2 w = tab[g];
        float2 q0 = dec2_e4m3(w.x), q1 = dec2_e4m3(w.x >> 16);
        float2 q2 = dec2_e4m3(w.y), q3 = dec2_e4m3(w.y >> 16);
        s0 += q0.x; s1 += q0.y; s2 += q1.x; s3 += q1.y;
        s4 += q2.x; s5 += q2.y; s6 += q3.x; s7 += q3.y;
    }
#pragma unroll
    for (int off = 1; off < GSZ; off <<= 1) {
        s0 += __shfl_xor(s0, off, GSZ); s1 += __shfl_xor(s1, off, GSZ);
        s2 += __shfl_xor(s2, off, GSZ); s3 += __shfl_xor(s3, off, GSZ);
        s4 += __shfl_xor(s4, off, GSZ); s5 += __shfl_xor(s5, off, GSZ);
        s6 += __shfl_xor(s6, off, GSZ); s7 += __shfl_xor(s7, off, GSZ);
    }
    float dv = rsqrtf((float)(e1 - e0) + 1.0f);
    int c = lane & 7;
    float sc = s0;
    sc = (c == 1) ? s1 : sc; sc = (c == 2) ? s2 : sc; sc = (c == 3) ? s3 : sc;
    sc = (c == 4) ? s4 : sc; sc = (c == 5) ? s5 : sc; sc = (c == 6) ? s6 : sc;
    sc = (c == 7) ? s7 : sc;
    float h = elu(dv * sc + b2[c]);
    float acc = 0.f;
#pragma unroll
    for (int k = 0; k < HID; ++k)
        acc = fmaf(__shfl(h, k, GSZ), W3[k * HID + c], acc);
    unsigned int part = enc_e4m3(dv * acc) << ((c & 3) * 8);
    part |= __shfl_xor(part, 1, GSZ);
    part |= __shfl_xor(part, 2, GSZ);
    unsigned int hiw = __shfl(part, 4, GSZ);
    if (lane == 0) {
        __builtin_nontemporal_store(part, &t3[g].x);
        __builtin_nontemporal_store(hiw, &t3[g].y);
    }
}

// layer3: 8ch fp8 table; epilogue b3->elu; fused mean-pool
__global__ void __launch_bounds__(256) agg3_kernel(
        const uint2* __restrict__ tab, const int* __restrict__ ptr,
        const int* __restrict__ ssrc, const float* __restrict__ b3,
        double* __restrict__ pooled, int N) {
    int g = blockIdx.x * (256 / GSZ) + (threadIdx.x >> 4);
    int lane = threadIdx.x & (GSZ - 1);
    float vv = 0.f;
    if (g < N) {
        int e0 = ptr[g], e1 = ptr[g + 1];
        float s0 = 0.f, s1 = 0.f, s2 = 0.f, s3 = 0.f, s4 = 0.f, s5 = 0.f, s6 = 0.f, s7 = 0.f;
        for (int k = e0 + lane; k < e1; k += GSZ) {
            uint2 w = tab[nt_load_i(&ssrc[k])];
            float2 q0 = dec2_e4m3(w.x), q1 = dec2_e4m3(w.x >> 16);
            float2 q2 = dec2_e4m3(w.y), q3 = dec2_e4m3(w.y >> 16);
            s0 += q0.x; s1 += q0.y; s2 += q1.x; s3 += q1.y;
            s4 += q2.x; s5 += q2.y; s6 += q3.x; s7 += q3.y;
        }
        if (lane == 0) {  // self-loop
            uint2 w = tab[g];
            float2 q0 = dec2_e4m3(w.x), q1 = dec2_e4m3(w.x >> 16);
            float2 q2 = dec2_e4m3(w.y), q3 = dec2_e4m3(w.y >> 16);
            s0 += q0.x; s1 += q0.y; s2 += q1.x; s3 += q1.y;
            s4 += q2.x; s5 += q2.y; s6 += q3.x; s7 += q3.y;
        }
#pragma unroll
        for (int off = 1; off < GSZ; off <<= 1) {
            s0 += __shfl_xor(s0, off, GSZ); s1 += __shfl_xor(s1, off, GSZ);
            s2 += __shfl_xor(s2, off, GSZ); s3 += __shfl_xor(s3, off, GSZ);
            s4 += __shfl_xor(s4, off, GSZ); s5 += __shfl_xor(s5, off, GSZ);
            s6 += __shfl_xor(s6, off, GSZ); s7 += __shfl_xor(s7, off, GSZ);
        }
        float dv = rsqrtf((float)(e1 - e0) + 1.0f);
        int c = lane & 7;
        float sc = s0;
        sc = (c == 1) ? s1 : sc; sc = (c == 2) ? s2 : sc; sc = (c == 3) ? s3 : sc;
        sc = (c == 4) ? s4 : sc; sc = (c == 5) ? s5 : sc; sc = (c == 6) ? s6 : sc;
        sc = (c == 7) ? s7 : sc;
        if (lane < 8) vv = elu(dv * sc + b3[c]);
    }
    // cross-group reduce within wave: lanes {0-7,16-23,32-39,48-55} hold channel values
    vv += __shfl_down(vv, 32);
    vv += __shfl_down(vv, 16);
    __shared__ float sm[4][HID];
    int wl = threadIdx.x & 63, wv = threadIdx.x >> 6;
    if (wl < 8) sm[wv][wl] = vv;
    __syncthreads();
    if (threadIdx.x < 8) {
        float s = sm[0][threadIdx.x] + sm[1][threadIdx.x] + sm[2][threadIdx.x] + sm[3][threadIdx.x];
        atomicAdd(&pooled[threadIdx.x], (double)s);
    }
}

__global__ void head_kernel(const double* __restrict__ pooled, const float* __restrict__ Wr1,
                            const float* __restrict__ br1, const float* __restrict__ Wr2,
                            const float* __restrict__ br2, float* __restrict__ out, int N) {
    if (threadIdx.x != 0 || blockIdx.x != 0) return;
    float p[HID];
#pragma unroll
    for (int k = 0; k < HID; ++k) p[k] = (float)(pooled[k] / (double)N);
    float hdn[HID];
#pragma unroll
    for (int j = 0; j < HID; ++j) {
        float s = br1[j];
#pragma unroll
        for (int k = 0; k < HID; ++k) s += p[k] * Wr1[k * HID + j];
        hdn[j] = elu(s);
    }
    float v = br2[0];
#pragma unroll
    for (int j = 0; j < HID; ++j) v += hdn[j] * Wr2[j];
    out[0] = v;
}

extern "C" void kernel_launch(void* const* d_in, const int* in_sizes, int n_in,
                              void* d_out, int out_size, void* d_ws, size_t ws_size,
                              hipStream_t stream) {
    const float* x   = (const float*)d_in[0];
    const int*   ei  = (const int*)d_in[1];
    const float* W1  = (const float*)d_in[2];
    const float* b1  = (const float*)d_in[3];
    const float* W2  = (const float*)d_in[4];
    const float* b2  = (const float*)d_in[5];
    const float* W3  = (const float*)d_in[6];
    const float* b3  = (const float*)d_in[7];
    const float* Wr1 = (const float*)d_in[8];
    const float* br1 = (const float*)d_in[9];
    const float* Wr2 = (const float*)d_in[10];
    const float* br2 = (const float*)d_in[11];
    float* out = (float*)d_out;

    const int N = NNODES;
    const int E = in_sizes[1] / 2;
    const int* srcp = ei;      // edge_index[0]
    const int* dstp = ei + E;  // edge_index[1]

    // workspace layout (~77 MB)
    double* pooled    = (double*)d_ws;                       // 8 doubles
    unsigned int* t1  = (unsigned int*)(pooled + HID);       // N x 4B (2MB)
    uint2* t2         = (uint2*)(t1 + N);                    // N x 8B (4MB)
    uint2* t3         = t2 + N;                              // N x 8B (4MB)
    int* gbinhist     = (int*)(t3 + N);                      // NBIN
    int* binexcl      = gbinhist + NBIN;                     // NBIN
    int* bsum         = binexcl + NBIN;                      // 1024
    int* ptr_bins     = bsum + 1024;                         // NBIN+1
    int* gcursor      = ptr_bins + NBIN + 1;                 // NBIN
    int* ptr          = gcursor + NBIN;                      // N+1
    int* ssrc         = ptr + N + 1;                         // E (64MB)

    hipMemsetAsync(gbinhist, 0, NBIN * sizeof(int), stream);
    hipMemsetAsync(pooled, 0, HID * sizeof(double), stream);

    const int BLK = 256;
    const int aggGrid = (N * GSZ + BLK - 1) / BLK;  // 16 lanes per dst

    // CSR build
    binhist_kernel<<<128, 1024, 0, stream>>>(dstp, E, gbinhist);
    scan1_kernel<<<1, SCAN_BLK, 0, stream>>>(gbinhist, binexcl, bsum, NBIN);
    scan2_kernel<<<1, SCAN_BLK, 0, stream>>>(bsum, 1);
    scan3b_kernel<<<(NBIN + BLK - 1) / BLK, BLK, 0, stream>>>(binexcl, bsum, ptr_bins, gcursor, E);
    binscatter_kernel<<<SGRID, 1024, 0, stream>>>(srcp, dstp, E, gcursor, ssrc);
    binsort_kernel<<<NBIN, 512, 0, stream>>>(ptr_bins, ssrc, ptr, x, t1, N, E);

    // 3 gather passes, wave-cooperative (16 lanes/dst)
    agg1_kernel<<<aggGrid, BLK, 0, stream>>>(t1, ptr, ssrc, W1, b1, W2, t2, N);
    agg2_kernel<<<aggGrid, BLK, 0, stream>>>(t2, ptr, ssrc, b2, W3, t3, N);
    agg3_kernel<<<aggGrid, BLK, 0, stream>>>(t3, ptr, ssrc, b3, pooled, N);

    head_kernel<<<1, 64, 0, stream>>>(pooled, Wr1, br1, Wr2, br2, out, N);
}

// Round 11
// 847.217 us; speedup vs baseline: 1.1532x; 1.1532x over previous
//
#include <hip/hip_runtime.h>
#include <hip/hip_fp16.h>

#define NNODES 500000
#define HID 8
#define BIN_SHIFT 9
#define BINW 512               // nodes per bin
#define NBIN 977               // ceil(500000/512)
#define SCAN_BLK 1024
#define SGRID 256              // binscatter blocks (1/CU)
#define CAP 24                 // LDS bucket capacity per bin
#define BUFCAP 18432           // binsort staging cap (mean 16384, +16 sigma)
#define AGRID 512              // agg blocks: limit in-flight nodes -> small L2 window
#define ABLK 256

typedef int intx4 __attribute__((ext_vector_type(4)));

__device__ __forceinline__ unsigned int packh2(float a, float b) {
    __half2 h = __floats2half2_rn(a, b);
    return *reinterpret_cast<unsigned int*>(&h);
}
__device__ __forceinline__ float2 unpackh2(unsigned int u) {
    __half2 h = *reinterpret_cast<__half2*>(&u);
    return __half22float2(h);
}
__device__ __forceinline__ float elu(float t) { return t > 0.0f ? t : expm1f(t); }
__device__ __forceinline__ int nt_load_i(const int* p) { return __builtin_nontemporal_load(p); }
__device__ __forceinline__ intx4 nt_load_i4(const intx4* p) { return __builtin_nontemporal_load(p); }

// software e4m3 encode (RNE)
__device__ __forceinline__ unsigned int enc_e4m3(float x) {
    unsigned sgn = (__float_as_uint(x) >> 31) << 7;
    float ax = fabsf(x);
    if (ax >= 448.f) return sgn | 0x7E;
    if (ax < 0.015625f) {
        unsigned q = (unsigned)__float2int_rn(ax * 512.0f);
        return sgn | q;
    }
    unsigned u = __float_as_uint(ax);
    int te = (int)((u >> 23) & 0xFF) - 120;
    unsigned m = u & 0x7FFFFF;
    unsigned r = (m + 0x7FFFF + ((m >> 20) & 1)) >> 20;
    unsigned code = ((unsigned)te << 3) + r;
    if (code > 0x7E) code = 0x7E;
    return sgn | code;
}

// VALU e4m3 decode, 2 bytes -> float2, exact (no LUT, no LDS)
__device__ __forceinline__ float2 dec2_e4m3(unsigned int b01) {
    unsigned int x = (b01 & 0xFFu) | ((b01 & 0xFF00u) << 8);
    unsigned int h = ((x & 0x00800080u) << 8) | ((x & 0x007F007Fu) << 7);
    __half2 hv = *reinterpret_cast<__half2*>(&h);
    const __half2 s256 = __floats2half2_rn(256.0f, 256.0f);
    hv = __hmul2(hv, s256);
    return __half22float2(hv);
}

// ================= CSR build =================
__global__ void binhist_kernel(const int* __restrict__ dst, int E, int* __restrict__ gbinhist) {
    __shared__ int hist[NBIN];
    for (int b = threadIdx.x; b < NBIN; b += blockDim.x) hist[b] = 0;
    __syncthreads();
    int stride = gridDim.x * blockDim.x;
    const intx4* d4 = (const intx4*)dst;
    int n4 = E >> 2;
    for (int e = blockIdx.x * blockDim.x + threadIdx.x; e < n4; e += stride) {
        intx4 d = nt_load_i4(&d4[e]);
        atomicAdd(&hist[d.x >> BIN_SHIFT], 1);
        atomicAdd(&hist[d.y >> BIN_SHIFT], 1);
        atomicAdd(&hist[d.z >> BIN_SHIFT], 1);
        atomicAdd(&hist[d.w >> BIN_SHIFT], 1);
    }
    int tail0 = n4 << 2;
    for (int e = tail0 + blockIdx.x * blockDim.x + threadIdx.x; e < E; e += stride)
        atomicAdd(&hist[dst[e] >> BIN_SHIFT], 1);
    __syncthreads();
    for (int b = threadIdx.x; b < NBIN; b += blockDim.x) {
        int c = hist[b];
        if (c) atomicAdd(&gbinhist[b], c);
    }
}

__global__ void scan1_kernel(const int* __restrict__ deg, int* __restrict__ excl,
                             int* __restrict__ bsum, int N) {
    __shared__ int sm[SCAN_BLK];
    int tid = threadIdx.x;
    int gid = blockIdx.x * SCAN_BLK + tid;
    int v = (gid < N) ? deg[gid] : 0;
    int x = v;
    sm[tid] = x;
    __syncthreads();
    for (int off = 1; off < SCAN_BLK; off <<= 1) {
        int t = (tid >= off) ? sm[tid - off] : 0;
        __syncthreads();
        x += t;
        sm[tid] = x;
        __syncthreads();
    }
    if (gid < N) excl[gid] = x - v;
    if (tid == SCAN_BLK - 1) bsum[blockIdx.x] = x;
}

__global__ void scan2_kernel(int* __restrict__ bsum, int nb) {
    __shared__ int sm[SCAN_BLK];
    int tid = threadIdx.x;
    int v = (tid < nb) ? bsum[tid] : 0;
    int x = v;
    sm[tid] = x;
    __syncthreads();
    for (int off = 1; off < SCAN_BLK; off <<= 1) {
        int t = (tid >= off) ? sm[tid - off] : 0;
        __syncthreads();
        x += t;
        sm[tid] = x;
        __syncthreads();
    }
    if (tid < nb) bsum[tid] = x - v;
}

__global__ void scan3b_kernel(const int* __restrict__ binexcl, const int* __restrict__ bsum,
                              int* __restrict__ ptr_bins, int* __restrict__ gcursor, int E) {
    int i = blockIdx.x * blockDim.x + threadIdx.x;
    if (i < NBIN) {
        int p = binexcl[i] + bsum[i / SCAN_BLK];
        ptr_bins[i] = p;
        gcursor[i] = p;
    }
    if (i == 0) ptr_bins[NBIN] = E;
}

// LDS-coalesced scatter: deposit into per-bin buckets; flush 16-word (64B) groups
__global__ void __launch_bounds__(1024) binscatter_kernel(
        const int* __restrict__ src, const int* __restrict__ dst,
        int E, int* __restrict__ gcursor, int* __restrict__ packed) {
    __shared__ int cnt[NBIN];
    __shared__ int bucket[NBIN][CAP];
    __shared__ int fq_bin[NBIN];
    __shared__ int fq_pos[NBIN];
    __shared__ int fq_n;
    int tid = threadIdx.x;
    int slice = (E + SGRID - 1) / SGRID;
    int e0 = blockIdx.x * slice;
    int e1 = min(E, e0 + slice);
    if (e0 >= e1) return;
    for (int b = tid; b < NBIN; b += 1024) cnt[b] = 0;
    if (tid == 0) fq_n = 0;
    __syncthreads();
    for (int base = e0; base < e1; base += 1024) {
        int e = base + tid;
        if (e < e1) {
            int d = nt_load_i(&dst[e]);
            int s = nt_load_i(&src[e]);
            int b = d >> BIN_SHIFT;
            int val = (s << BIN_SHIFT) | (d & (BINW - 1));
            int slot = atomicAdd(&cnt[b], 1);
            if (slot < CAP) bucket[b][slot] = val;
            else {
                int gp = atomicAdd(&gcursor[b], 1);
                packed[gp] = val;
            }
        }
        __syncthreads();
        if (tid < NBIN) {
            int c = min(cnt[tid], CAP);
            if (c >= 16) {
                int idx = atomicAdd(&fq_n, 1);
                fq_bin[idx] = tid;
                fq_pos[idx] = atomicAdd(&gcursor[tid], 16);
            }
        }
        __syncthreads();
        int nf = fq_n;
        for (int w = tid; w < nf * 16; w += 1024) {
            int q = w >> 4, j = w & 15;
            packed[fq_pos[q] + j] = bucket[fq_bin[q]][j];
        }
        __syncthreads();
        if (tid < NBIN) {
            int c = min(cnt[tid], CAP);
            if (c >= 16) {
                int rem = c - 16;
                for (int j = 0; j < rem; ++j) bucket[tid][j] = bucket[tid][16 + j];
                cnt[tid] = rem;
            } else {
                cnt[tid] = c;
            }
        }
        if (tid == 0) fq_n = 0;
        __syncthreads();
    }
    if (tid < NBIN) {
        int c = min(cnt[tid], CAP);
        if (c > 0) {
            int pos = atomicAdd(&gcursor[tid], c);
            for (int j = 0; j < c; ++j) packed[pos + j] = bucket[tid][j];
        }
    }
}

// per-bin LDS sort (512-node bins) -> final ssrc (in place), ptr, t1 (= dinv*x fp16x2)
__global__ void __launch_bounds__(512) binsort_kernel(
        const int* __restrict__ ptr_bins, int* __restrict__ ssrc,
        int* __restrict__ ptr, const float* __restrict__ x,
        unsigned int* __restrict__ t1, int N, int E) {
    __shared__ int buf[BUFCAP];
    __shared__ int hist[BINW];
    __shared__ int scn[BINW];
    __shared__ int cursor[BINW];
    int bin = blockIdx.x;
    int tid = threadIdx.x;
    int base = ptr_bins[bin];
    int len = min(ptr_bins[bin + 1] - base, BUFCAP);
    int node_base = bin << BIN_SHIFT;
    int nn = min(BINW, N - node_base);
    hist[tid] = 0;
    __syncthreads();
    for (int k = tid; k < len; k += 512) {
        int v = nt_load_i(&ssrc[base + k]);
        buf[k] = v;
        atomicAdd(&hist[v & (BINW - 1)], 1);
    }
    __syncthreads();
    int orig = hist[tid];
    int x_ = orig;
    scn[tid] = x_;
    __syncthreads();
    for (int off = 1; off < BINW; off <<= 1) {
        int t = (tid >= off) ? scn[tid - off] : 0;
        __syncthreads();
        x_ += t;
        scn[tid] = x_;
        __syncthreads();
    }
    if (tid < nn) {
        int ex = x_ - orig;
        int node = node_base + tid;
        ptr[node] = base + ex;
        cursor[tid] = ex;
        float dv = rsqrtf((float)orig + 1.0f);  // self-loop => deg+1
        float2 xv = *reinterpret_cast<const float2*>(x + 2 * (size_t)node);
        t1[node] = packh2(dv * xv.x, dv * xv.y);
    }
    if (bin == NBIN - 1 && tid == 0) ptr[N] = E;
    __syncthreads();
    for (int k = tid; k < len; k += 512) {
        int v = buf[k];
        int pos = atomicAdd(&cursor[v & (BINW - 1)], 1);
        ssrc[base + pos] = v >> BIN_SHIFT;
    }
}

// ========== layer pipeline: thread-per-node, GRID-LIMITED (small L2 window) ==========
__global__ void __launch_bounds__(ABLK) agg1_kernel(
        const unsigned int* __restrict__ t1, const int* __restrict__ ptr,
        const int* __restrict__ ssrc, const float* __restrict__ W1,
        const float* __restrict__ b1, const float* __restrict__ W2,
        uint2* __restrict__ t2, int N) {
    int stride = AGRID * ABLK;
    for (int i = blockIdx.x * ABLK + threadIdx.x; i < N; i += stride) {
        float2 s = unpackh2(t1[i]);  // self-loop
        int e0 = ptr[i], e1 = ptr[i + 1];
#pragma unroll 4
        for (int k = e0; k < e1; ++k) {
            float2 p = unpackh2(t1[nt_load_i(&ssrc[k])]);
            s.x += p.x; s.y += p.y;
        }
        float dv = rsqrtf((float)(e1 - e0) + 1.0f);
        float h[HID];
#pragma unroll
        for (int c = 0; c < HID; ++c)
            h[c] = elu(dv * (s.x * W1[c] + s.y * W1[HID + c]) + b1[c]);
        float g[HID];
#pragma unroll
        for (int c = 0; c < HID; ++c) {
            float acc = 0.0f;
#pragma unroll
            for (int k = 0; k < HID; ++k) acc += h[k] * W2[k * HID + c];
            g[c] = dv * acc;
        }
        unsigned int lo = enc_e4m3(g[0]) | (enc_e4m3(g[1]) << 8) |
                          (enc_e4m3(g[2]) << 16) | (enc_e4m3(g[3]) << 24);
        unsigned int hi = enc_e4m3(g[4]) | (enc_e4m3(g[5]) << 8) |
                          (enc_e4m3(g[6]) << 16) | (enc_e4m3(g[7]) << 24);
        __builtin_nontemporal_store(lo, &t2[i].x);
        __builtin_nontemporal_store(hi, &t2[i].y);
    }
}

__global__ void __launch_bounds__(ABLK) agg2_kernel(
        const uint2* __restrict__ tab, const int* __restrict__ ptr,
        const int* __restrict__ ssrc, const float* __restrict__ b2,
        const float* __restrict__ W3, uint2* __restrict__ t3, int N) {
    int stride = AGRID * ABLK;
    for (int i = blockIdx.x * ABLK + threadIdx.x; i < N; i += stride) {
        uint2 u = tab[i];
        float2 p0 = dec2_e4m3(u.x), p1 = dec2_e4m3(u.x >> 16);
        float2 p2 = dec2_e4m3(u.y), p3 = dec2_e4m3(u.y >> 16);
        float s0 = p0.x, s1 = p0.y, s2 = p1.x, s3 = p1.y;
        float s4 = p2.x, s5 = p2.y, s6 = p3.x, s7 = p3.y;
        int e0 = ptr[i], e1 = ptr[i + 1];
#pragma unroll 4
        for (int k = e0; k < e1; ++k) {
            uint2 w = tab[nt_load_i(&ssrc[k])];
            float2 q0 = dec2_e4m3(w.x), q1 = dec2_e4m3(w.x >> 16);
            float2 q2 = dec2_e4m3(w.y), q3 = dec2_e4m3(w.y >> 16);
            s0 += q0.x; s1 += q0.y; s2 += q1.x; s3 += q1.y;
            s4 += q2.x; s5 += q2.y; s6 += q3.x; s7 += q3.y;
        }
        float dv = rsqrtf((float)(e1 - e0) + 1.0f);
        float h[HID] = {elu(dv * s0 + b2[0]), elu(dv * s1 + b2[1]),
                        elu(dv * s2 + b2[2]), elu(dv * s3 + b2[3]),
                        elu(dv * s4 + b2[4]), elu(dv * s5 + b2[5]),
                        elu(dv * s6 + b2[6]), elu(dv * s7 + b2[7])};
        float g[HID];
#pragma unroll
        for (int c = 0; c < HID; ++c) {
            float acc = 0.0f;
#pragma unroll
            for (int k = 0; k < HID; ++k) acc += h[k] * W3[k * HID + c];
            g[c] = dv * acc;
        }
        unsigned int lo = enc_e4m3(g[0]) | (enc_e4m3(g[1]) << 8) |
                          (enc_e4m3(g[2]) << 16) | (enc_e4m3(g[3]) << 24);
        unsigned int hi = enc_e4m3(g[4]) | (enc_e4m3(g[5]) << 8) |
                          (enc_e4m3(g[6]) << 16) | (enc_e4m3(g[7]) << 24);
        __builtin_nontemporal_store(lo, &t3[i].x);
        __builtin_nontemporal_store(hi, &t3[i].y);
    }
}

__global__ void __launch_bounds__(ABLK) agg3_kernel(
        const uint2* __restrict__ tab, const int* __restrict__ ptr,
        const int* __restrict__ ssrc, const float* __restrict__ b3,
        double* __restrict__ pooled, int N) {
    float v[HID];
#pragma unroll
    for (int c = 0; c < HID; ++c) v[c] = 0.0f;
    int stride = AGRID * ABLK;
    for (int i = blockIdx.x * ABLK + threadIdx.x; i < N; i += stride) {
        uint2 u = tab[i];
        float2 p0 = dec2_e4m3(u.x), p1 = dec2_e4m3(u.x >> 16);
        float2 p2 = dec2_e4m3(u.y), p3 = dec2_e4m3(u.y >> 16);
        float s0 = p0.x, s1 = p0.y, s2 = p1.x, s3 = p1.y;
        float s4 = p2.x, s5 = p2.y, s6 = p3.x, s7 = p3.y;
        int e0 = ptr[i], e1 = ptr[i + 1];
#pragma unroll 4
        for (int k = e0; k < e1; ++k) {
            uint2 w = tab[nt_load_i(&ssrc[k])];
            float2 q0 = dec2_e4m3(w.x), q1 = dec2_e4m3(w.x >> 16);
            float2 q2 = dec2_e4m3(w.y), q3 = dec2_e4m3(w.y >> 16);
            s0 += q0.x; s1 += q0.y; s2 += q1.x; s3 += q1.y;
            s4 += q2.x; s5 += q2.y; s6 += q3.x; s7 += q3.y;
        }
        float dv = rsqrtf((float)(e1 - e0) + 1.0f);
        v[0] += elu(dv * s0 + b3[0]); v[1] += elu(dv * s1 + b3[1]);
        v[2] += elu(dv * s2 + b3[2]); v[3] += elu(dv * s3 + b3[3]);
        v[4] += elu(dv * s4 + b3[4]); v[5] += elu(dv * s5 + b3[5]);
        v[6] += elu(dv * s6 + b3[6]); v[7] += elu(dv * s7 + b3[7]);
    }
    // block reduce the per-thread pooled partials
#pragma unroll
    for (int c = 0; c < HID; ++c) {
        float s = v[c];
        for (int off = 32; off > 0; off >>= 1) s += __shfl_down(s, off);
        v[c] = s;
    }
    __shared__ float sm[4][HID];
    int lane = threadIdx.x & 63;
    int wv = threadIdx.x >> 6;
    if (lane == 0) {
#pragma unroll
        for (int c = 0; c < HID; ++c) sm[wv][c] = v[c];
    }
    __syncthreads();
    if (threadIdx.x == 0) {
#pragma unroll
        for (int c = 0; c < HID; ++c) {
            float s = sm[0][c] + sm[1][c] + sm[2][c] + sm[3][c];
            atomicAdd(&pooled[c], (double)s);
        }
    }
}

__global__ void head_kernel(const double* __restrict__ pooled, const float* __restrict__ Wr1,
                            const float* __restrict__ br1, const float* __restrict__ Wr2,
                            const float* __restrict__ br2, float* __restrict__ out, int N) {
    if (threadIdx.x != 0 || blockIdx.x != 0) return;
    float p[HID];
#pragma unroll
    for (int k = 0; k < HID; ++k) p[k] = (float)(pooled[k] / (double)N);
    float hdn[HID];
#pragma unroll
    for (int j = 0; j < HID; ++j) {
        float s = br1[j];
#pragma unroll
        for (int k = 0; k < HID; ++k) s += p[k] * Wr1[k * HID + j];
        hdn[j] = elu(s);
    }
    float v = br2[0];
#pragma unroll
    for (int j = 0; j < HID; ++j) v += hdn[j] * Wr2[j];
    out[0] = v;
}

extern "C" void kernel_launch(void* const* d_in, const int* in_sizes, int n_in,
                              void* d_out, int out_size, void* d_ws, size_t ws_size,
                              hipStream_t stream) {
    const float* x   = (const float*)d_in[0];
    const int*   ei  = (const int*)d_in[1];
    const float* W1  = (const float*)d_in[2];
    const float* b1  = (const float*)d_in[3];
    const float* W2  = (const float*)d_in[4];
    const float* b2  = (const float*)d_in[5];
    const float* W3  = (const float*)d_in[6];
    const float* b3  = (const float*)d_in[7];
    const float* Wr1 = (const float*)d_in[8];
    const float* br1 = (const float*)d_in[9];
    const float* Wr2 = (const float*)d_in[10];
    const float* br2 = (const float*)d_in[11];
    float* out = (float*)d_out;

    const int N = NNODES;
    const int E = in_sizes[1] / 2;
    const int* srcp = ei;      // edge_index[0]
    const int* dstp = ei + E;  // edge_index[1]

    // workspace layout (~77 MB)
    double* pooled    = (double*)d_ws;                       // 8 doubles
    unsigned int* t1  = (unsigned int*)(pooled + HID);       // N x 4B (2MB)
    uint2* t2         = (uint2*)(t1 + N);                    // N x 8B (4MB)
    uint2* t3         = t2 + N;                              // N x 8B (4MB)
    int* gbinhist     = (int*)(t3 + N);                      // NBIN
    int* binexcl      = gbinhist + NBIN;                     // NBIN
    int* bsum         = binexcl + NBIN;                      // 1024
    int* ptr_bins     = bsum + 1024;                         // NBIN+1
    int* gcursor      = ptr_bins + NBIN + 1;                 // NBIN
    int* ptr          = gcursor + NBIN;                      // N+1
    int* ssrc         = ptr + N + 1;                         // E (64MB)

    hipMemsetAsync(gbinhist, 0, NBIN * sizeof(int), stream);
    hipMemsetAsync(pooled, 0, HID * sizeof(double), stream);

    const int BLK = 256;

    // CSR build
    binhist_kernel<<<128, 1024, 0, stream>>>(dstp, E, gbinhist);
    scan1_kernel<<<1, SCAN_BLK, 0, stream>>>(gbinhist, binexcl, bsum, NBIN);
    scan2_kernel<<<1, SCAN_BLK, 0, stream>>>(bsum, 1);
    scan3b_kernel<<<(NBIN + BLK - 1) / BLK, BLK, 0, stream>>>(binexcl, bsum, ptr_bins, gcursor, E);
    binscatter_kernel<<<SGRID, 1024, 0, stream>>>(srcp, dstp, E, gcursor, ssrc);
    binsort_kernel<<<NBIN, 512, 0, stream>>>(ptr_bins, ssrc, ptr, x, t1, N, E);

    // 3 gather passes, thread-per-node, grid-limited for L2 table residency
    agg1_kernel<<<AGRID, ABLK, 0, stream>>>(t1, ptr, ssrc, W1, b1, W2, t2, N);
    agg2_kernel<<<AGRID, ABLK, 0, stream>>>(t2, ptr, ssrc, b2, W3, t3, N);
    agg3_kernel<<<AGRID, ABLK, 0, stream>>>(t3, ptr, ssrc, b3, pooled, N);

    head_kernel<<<1, 64, 0, stream>>>(pooled, Wr1, br1, Wr2, br2, out, N);
}

// Round 12
// 712.655 us; speedup vs baseline: 1.3709x; 1.1888x over previous
//
#include <hip/hip_runtime.h>
#include <hip/hip_fp16.h>

#define NNODES 500000
#define HID 8
#define BIN_SHIFT 9
#define BINW 512               // nodes per bin
#define NBIN 977               // ceil(500000/512)
#define SCAN_BLK 1024
#define SGRID 256              // binscatter blocks (1/CU)
#define CAP 28                 // LDS bucket capacity per bin
#define BATCH 4096             // edges deposited between flush cycles
#define BUFCAP 18432           // binsort staging cap (mean 16384, +16 sigma)
#define AGRID 512              // agg blocks: limit in-flight nodes -> small L2 window
#define ABLK 256

typedef int intx4 __attribute__((ext_vector_type(4)));

__device__ __forceinline__ unsigned int packh2(float a, float b) {
    __half2 h = __floats2half2_rn(a, b);
    return *reinterpret_cast<unsigned int*>(&h);
}
__device__ __forceinline__ float2 unpackh2(unsigned int u) {
    __half2 h = *reinterpret_cast<__half2*>(&u);
    return __half22float2(h);
}
__device__ __forceinline__ float elu(float t) { return t > 0.0f ? t : expm1f(t); }
__device__ __forceinline__ int nt_load_i(const int* p) { return __builtin_nontemporal_load(p); }
__device__ __forceinline__ intx4 nt_load_i4(const intx4* p) { return __builtin_nontemporal_load(p); }

// software e4m3 encode (RNE)
__device__ __forceinline__ unsigned int enc_e4m3(float x) {
    unsigned sgn = (__float_as_uint(x) >> 31) << 7;
    float ax = fabsf(x);
    if (ax >= 448.f) return sgn | 0x7E;
    if (ax < 0.015625f) {
        unsigned q = (unsigned)__float2int_rn(ax * 512.0f);
        return sgn | q;
    }
    unsigned u = __float_as_uint(ax);
    int te = (int)((u >> 23) & 0xFF) - 120;
    unsigned m = u & 0x7FFFFF;
    unsigned r = (m + 0x7FFFF + ((m >> 20) & 1)) >> 20;
    unsigned code = ((unsigned)te << 3) + r;
    if (code > 0x7E) code = 0x7E;
    return sgn | code;
}

// VALU e4m3 decode, 2 bytes -> float2, exact (no LUT, no LDS)
__device__ __forceinline__ float2 dec2_e4m3(unsigned int b01) {
    unsigned int x = (b01 & 0xFFu) | ((b01 & 0xFF00u) << 8);
    unsigned int h = ((x & 0x00800080u) << 8) | ((x & 0x007F007Fu) << 7);
    __half2 hv = *reinterpret_cast<__half2*>(&h);
    const __half2 s256 = __floats2half2_rn(256.0f, 256.0f);
    hv = __hmul2(hv, s256);
    return __half22float2(hv);
}

// ================= CSR build =================
__global__ void binhist_kernel(const int* __restrict__ dst, int E, int* __restrict__ gbinhist) {
    __shared__ int hist[NBIN];
    for (int b = threadIdx.x; b < NBIN; b += blockDim.x) hist[b] = 0;
    __syncthreads();
    int stride = gridDim.x * blockDim.x;
    const intx4* d4 = (const intx4*)dst;
    int n4 = E >> 2;
    for (int e = blockIdx.x * blockDim.x + threadIdx.x; e < n4; e += stride) {
        intx4 d = nt_load_i4(&d4[e]);
        atomicAdd(&hist[d.x >> BIN_SHIFT], 1);
        atomicAdd(&hist[d.y >> BIN_SHIFT], 1);
        atomicAdd(&hist[d.z >> BIN_SHIFT], 1);
        atomicAdd(&hist[d.w >> BIN_SHIFT], 1);
    }
    int tail0 = n4 << 2;
    for (int e = tail0 + blockIdx.x * blockDim.x + threadIdx.x; e < E; e += stride)
        atomicAdd(&hist[dst[e] >> BIN_SHIFT], 1);
    __syncthreads();
    for (int b = threadIdx.x; b < NBIN; b += blockDim.x) {
        int c = hist[b];
        if (c) atomicAdd(&gbinhist[b], c);
    }
}

__global__ void scan1_kernel(const int* __restrict__ deg, int* __restrict__ excl,
                             int* __restrict__ bsum, int N) {
    __shared__ int sm[SCAN_BLK];
    int tid = threadIdx.x;
    int gid = blockIdx.x * SCAN_BLK + tid;
    int v = (gid < N) ? deg[gid] : 0;
    int x = v;
    sm[tid] = x;
    __syncthreads();
    for (int off = 1; off < SCAN_BLK; off <<= 1) {
        int t = (tid >= off) ? sm[tid - off] : 0;
        __syncthreads();
        x += t;
        sm[tid] = x;
        __syncthreads();
    }
    if (gid < N) excl[gid] = x - v;
    if (tid == SCAN_BLK - 1) bsum[blockIdx.x] = x;
}

__global__ void scan2_kernel(int* __restrict__ bsum, int nb) {
    __shared__ int sm[SCAN_BLK];
    int tid = threadIdx.x;
    int v = (tid < nb) ? bsum[tid] : 0;
    int x = v;
    sm[tid] = x;
    __syncthreads();
    for (int off = 1; off < SCAN_BLK; off <<= 1) {
        int t = (tid >= off) ? sm[tid - off] : 0;
        __syncthreads();
        x += t;
        sm[tid] = x;
        __syncthreads();
    }
    if (tid < nb) bsum[tid] = x - v;
}

__global__ void scan3b_kernel(const int* __restrict__ binexcl, const int* __restrict__ bsum,
                              int* __restrict__ ptr_bins, int* __restrict__ gcursor, int E) {
    int i = blockIdx.x * blockDim.x + threadIdx.x;
    if (i < NBIN) {
        int p = binexcl[i] + bsum[i / SCAN_BLK];
        ptr_bins[i] = p;
        gcursor[i] = p;
    }
    if (i == 0) ptr_bins[NBIN] = E;
}

// LDS-coalesced scatter; 4096-edge deposit batches (no syncs), then one flush cycle
__global__ void __launch_bounds__(1024) binscatter_kernel(
        const int* __restrict__ src, const int* __restrict__ dst,
        int E, int* __restrict__ gcursor, int* __restrict__ packed) {
    __shared__ int cnt[NBIN];
    __shared__ int bucket[NBIN][CAP];
    __shared__ int fq_bin[NBIN];
    __shared__ int fq_pos[NBIN];
    __shared__ int fq_n;
    int tid = threadIdx.x;
    int slice = (((E + SGRID - 1) / SGRID) + 3) & ~3;  // 16B-aligned slices
    int e0 = blockIdx.x * slice;
    int e1 = min(E, e0 + slice);
    if (e0 >= e1) return;
    for (int b = tid; b < NBIN; b += 1024) cnt[b] = 0;
    if (tid == 0) fq_n = 0;
    __syncthreads();
    for (int base = e0; base < e1; base += BATCH) {
        int bend = min(e1, base + BATCH);
        // ---- deposit (no syncs; atomics only) ----
        int k = base + tid * 4;
        if (k + 4 <= bend) {
            intx4 d = nt_load_i4((const intx4*)(dst + k));
            intx4 s = nt_load_i4((const intx4*)(src + k));
#pragma unroll
            for (int j = 0; j < 4; ++j) {
                int dd = (j == 0) ? d.x : (j == 1) ? d.y : (j == 2) ? d.z : d.w;
                int ss = (j == 0) ? s.x : (j == 1) ? s.y : (j == 2) ? s.z : s.w;
                int b = dd >> BIN_SHIFT;
                int val = (ss << BIN_SHIFT) | (dd & (BINW - 1));
                int slot = atomicAdd(&cnt[b], 1);
                if (slot < CAP) bucket[b][slot] = val;
                else { int gp = atomicAdd(&gcursor[b], 1); packed[gp] = val; }
            }
        } else {
            for (int kk = k; kk < bend; ++kk) {
                int dd = nt_load_i(&dst[kk]);
                int ss = nt_load_i(&src[kk]);
                int b = dd >> BIN_SHIFT;
                int val = (ss << BIN_SHIFT) | (dd & (BINW - 1));
                int slot = atomicAdd(&cnt[b], 1);
                if (slot < CAP) bucket[b][slot] = val;
                else { int gp = atomicAdd(&gcursor[b], 1); packed[gp] = val; }
            }
        }
        __syncthreads();
        // ---- flush select ----
        if (tid < NBIN) {
            int c = min(cnt[tid], CAP);
            if (c >= 16) {
                int idx = atomicAdd(&fq_n, 1);
                fq_bin[idx] = tid;
                fq_pos[idx] = atomicAdd(&gcursor[tid], 16);
            }
        }
        __syncthreads();
        // ---- coalesced group write ----
        int nf = fq_n;
        for (int w = tid; w < nf * 16; w += 1024) {
            int q = w >> 4, j = w & 15;
            packed[fq_pos[q] + j] = bucket[fq_bin[q]][j];
        }
        __syncthreads();
        // ---- compact remainders; reset ----
        if (tid < NBIN) {
            int c = min(cnt[tid], CAP);
            if (c >= 16) {
                int rem = c - 16;
                for (int j = 0; j < rem; ++j) bucket[tid][j] = bucket[tid][16 + j];
                cnt[tid] = rem;
            } else {
                cnt[tid] = c;
            }
        }
        if (tid == 0) fq_n = 0;
        __syncthreads();
    }
    // drain remainders (<16 each)
    if (tid < NBIN) {
        int c = min(cnt[tid], CAP);
        if (c > 0) {
            int pos = atomicAdd(&gcursor[tid], c);
            for (int j = 0; j < c; ++j) packed[pos + j] = bucket[tid][j];
        }
    }
}

// per-bin LDS sort (512-node bins) -> final ssrc (in place), ptr, t1 (= dinv*x fp16x2)
__global__ void __launch_bounds__(512) binsort_kernel(
        const int* __restrict__ ptr_bins, int* __restrict__ ssrc,
        int* __restrict__ ptr, const float* __restrict__ x,
        unsigned int* __restrict__ t1, int N, int E) {
    __shared__ int buf[BUFCAP];
    __shared__ int hist[BINW];
    __shared__ int scn[BINW];
    __shared__ int cursor[BINW];
    int bin = blockIdx.x;
    int tid = threadIdx.x;
    int base = ptr_bins[bin];
    int len = min(ptr_bins[bin + 1] - base, BUFCAP);
    int node_base = bin << BIN_SHIFT;
    int nn = min(BINW, N - node_base);
    hist[tid] = 0;
    __syncthreads();
    for (int k = tid; k < len; k += 512) {
        int v = nt_load_i(&ssrc[base + k]);
        buf[k] = v;
        atomicAdd(&hist[v & (BINW - 1)], 1);
    }
    __syncthreads();
    int orig = hist[tid];
    int x_ = orig;
    scn[tid] = x_;
    __syncthreads();
    for (int off = 1; off < BINW; off <<= 1) {
        int t = (tid >= off) ? scn[tid - off] : 0;
        __syncthreads();
        x_ += t;
        scn[tid] = x_;
        __syncthreads();
    }
    if (tid < nn) {
        int ex = x_ - orig;
        int node = node_base + tid;
        ptr[node] = base + ex;
        cursor[tid] = ex;
        float dv = rsqrtf((float)orig + 1.0f);  // self-loop => deg+1
        float2 xv = *reinterpret_cast<const float2*>(x + 2 * (size_t)node);
        t1[node] = packh2(dv * xv.x, dv * xv.y);
    }
    if (bin == NBIN - 1 && tid == 0) ptr[N] = E;
    __syncthreads();
    for (int k = tid; k < len; k += 512) {
        int v = buf[k];
        int pos = atomicAdd(&cursor[v & (BINW - 1)], 1);
        ssrc[base + pos] = v >> BIN_SHIFT;
    }
}

// ========== layer pipeline: thread-per-node, grid-limited, unroll-8 gathers ==========
__global__ void __launch_bounds__(ABLK) agg1_kernel(
        const unsigned int* __restrict__ t1, const int* __restrict__ ptr,
        const int* __restrict__ ssrc, const float* __restrict__ W1,
        const float* __restrict__ b1, const float* __restrict__ W2,
        uint2* __restrict__ t2, int N) {
    int stride = AGRID * ABLK;
    for (int i = blockIdx.x * ABLK + threadIdx.x; i < N; i += stride) {
        float2 s = unpackh2(t1[i]);  // self-loop
        int e0 = ptr[i], e1 = ptr[i + 1];
#pragma unroll 8
        for (int k = e0; k < e1; ++k) {
            float2 p = unpackh2(t1[nt_load_i(&ssrc[k])]);
            s.x += p.x; s.y += p.y;
        }
        float dv = rsqrtf((float)(e1 - e0) + 1.0f);
        float h[HID];
#pragma unroll
        for (int c = 0; c < HID; ++c)
            h[c] = elu(dv * (s.x * W1[c] + s.y * W1[HID + c]) + b1[c]);
        float g[HID];
#pragma unroll
        for (int c = 0; c < HID; ++c) {
            float acc = 0.0f;
#pragma unroll
            for (int k = 0; k < HID; ++k) acc += h[k] * W2[k * HID + c];
            g[c] = dv * acc;
        }
        unsigned int lo = enc_e4m3(g[0]) | (enc_e4m3(g[1]) << 8) |
                          (enc_e4m3(g[2]) << 16) | (enc_e4m3(g[3]) << 24);
        unsigned int hi = enc_e4m3(g[4]) | (enc_e4m3(g[5]) << 8) |
                          (enc_e4m3(g[6]) << 16) | (enc_e4m3(g[7]) << 24);
        __builtin_nontemporal_store(lo, &t2[i].x);
        __builtin_nontemporal_store(hi, &t2[i].y);
    }
}

__global__ void __launch_bounds__(ABLK) agg2_kernel(
        const uint2* __restrict__ tab, const int* __restrict__ ptr,
        const int* __restrict__ ssrc, const float* __restrict__ b2,
        const float* __restrict__ W3, uint2* __restrict__ t3, int N) {
    int stride = AGRID * ABLK;
    for (int i = blockIdx.x * ABLK + threadIdx.x; i < N; i += stride) {
        uint2 u = tab[i];
        float2 p0 = dec2_e4m3(u.x), p1 = dec2_e4m3(u.x >> 16);
        float2 p2 = dec2_e4m3(u.y), p3 = dec2_e4m3(u.y >> 16);
        float s0 = p0.x, s1 = p0.y, s2 = p1.x, s3 = p1.y;
        float s4 = p2.x, s5 = p2.y, s6 = p3.x, s7 = p3.y;
        int e0 = ptr[i], e1 = ptr[i + 1];
#pragma unroll 8
        for (int k = e0; k < e1; ++k) {
            uint2 w = tab[nt_load_i(&ssrc[k])];
            float2 q0 = dec2_e4m3(w.x), q1 = dec2_e4m3(w.x >> 16);
            float2 q2 = dec2_e4m3(w.y), q3 = dec2_e4m3(w.y >> 16);
            s0 += q0.x; s1 += q0.y; s2 += q1.x; s3 += q1.y;
            s4 += q2.x; s5 += q2.y; s6 += q3.x; s7 += q3.y;
        }
        float dv = rsqrtf((float)(e1 - e0) + 1.0f);
        float h[HID] = {elu(dv * s0 + b2[0]), elu(dv * s1 + b2[1]),
                        elu(dv * s2 + b2[2]), elu(dv * s3 + b2[3]),
                        elu(dv * s4 + b2[4]), elu(dv * s5 + b2[5]),
                        elu(dv * s6 + b2[6]), elu(dv * s7 + b2[7])};
        float g[HID];
#pragma unroll
        for (int c = 0; c < HID; ++c) {
            float acc = 0.0f;
#pragma unroll
            for (int k = 0; k < HID; ++k) acc += h[k] * W3[k * HID + c];
            g[c] = dv * acc;
        }
        unsigned int lo = enc_e4m3(g[0]) | (enc_e4m3(g[1]) << 8) |
                          (enc_e4m3(g[2]) << 16) | (enc_e4m3(g[3]) << 24);
        unsigned int hi = enc_e4m3(g[4]) | (enc_e4m3(g[5]) << 8) |
                          (enc_e4m3(g[6]) << 16) | (enc_e4m3(g[7]) << 24);
        __builtin_nontemporal_store(lo, &t3[i].x);
        __builtin_nontemporal_store(hi, &t3[i].y);
    }
}

__global__ void __launch_bounds__(ABLK) agg3_kernel(
        const uint2* __restrict__ tab, const int* __restrict__ ptr,
        const int* __restrict__ ssrc, const float* __restrict__ b3,
        double* __restrict__ pooled, int N) {
    float v[HID];
#pragma unroll
    for (int c = 0; c < HID; ++c) v[c] = 0.0f;
    int stride = AGRID * ABLK;
    for (int i = blockIdx.x * ABLK + threadIdx.x; i < N; i += stride) {
        uint2 u = tab[i];
        float2 p0 = dec2_e4m3(u.x), p1 = dec2_e4m3(u.x >> 16);
        float2 p2 = dec2_e4m3(u.y), p3 = dec2_e4m3(u.y >> 16);
        float s0 = p0.x, s1 = p0.y, s2 = p1.x, s3 = p1.y;
        float s4 = p2.x, s5 = p2.y, s6 = p3.x, s7 = p3.y;
        int e0 = ptr[i], e1 = ptr[i + 1];
#pragma unroll 8
        for (int k = e0; k < e1; ++k) {
            uint2 w = tab[nt_load_i(&ssrc[k])];
            float2 q0 = dec2_e4m3(w.x), q1 = dec2_e4m3(w.x >> 16);
            float2 q2 = dec2_e4m3(w.y), q3 = dec2_e4m3(w.y >> 16);
            s0 += q0.x; s1 += q0.y; s2 += q1.x; s3 += q1.y;
            s4 += q2.x; s5 += q2.y; s6 += q3.x; s7 += q3.y;
        }
        float dv = rsqrtf((float)(e1 - e0) + 1.0f);
        v[0] += elu(dv * s0 + b3[0]); v[1] += elu(dv * s1 + b3[1]);
        v[2] += elu(dv * s2 + b3[2]); v[3] += elu(dv * s3 + b3[3]);
        v[4] += elu(dv * s4 + b3[4]); v[5] += elu(dv * s5 + b3[5]);
        v[6] += elu(dv * s6 + b3[6]); v[7] += elu(dv * s7 + b3[7]);
    }
#pragma unroll
    for (int c = 0; c < HID; ++c) {
        float s = v[c];
        for (int off = 32; off > 0; off >>= 1) s += __shfl_down(s, off);
        v[c] = s;
    }
    __shared__ float sm[4][HID];
    int lane = threadIdx.x & 63;
    int wv = threadIdx.x >> 6;
    if (lane == 0) {
#pragma unroll
        for (int c = 0; c < HID; ++c) sm[wv][c] = v[c];
    }
    __syncthreads();
    if (threadIdx.x == 0) {
#pragma unroll
        for (int c = 0; c < HID; ++c) {
            float s = sm[0][c] + sm[1][c] + sm[2][c] + sm[3][c];
            atomicAdd(&pooled[c], (double)s);
        }
    }
}

__global__ void head_kernel(const double* __restrict__ pooled, const float* __restrict__ Wr1,
                            const float* __restrict__ br1, const float* __restrict__ Wr2,
                            const float* __restrict__ br2, float* __restrict__ out, int N) {
    if (threadIdx.x != 0 || blockIdx.x != 0) return;
    float p[HID];
#pragma unroll
    for (int k = 0; k < HID; ++k) p[k] = (float)(pooled[k] / (double)N);
    float hdn[HID];
#pragma unroll
    for (int j = 0; j < HID; ++j) {
        float s = br1[j];
#pragma unroll
        for (int k = 0; k < HID; ++k) s += p[k] * Wr1[k * HID + j];
        hdn[j] = elu(s);
    }
    float v = br2[0];
#pragma unroll
    for (int j = 0; j < HID; ++j) v += hdn[j] * Wr2[j];
    out[0] = v;
}

extern "C" void kernel_launch(void* const* d_in, const int* in_sizes, int n_in,
                              void* d_out, int out_size, void* d_ws, size_t ws_size,
                              hipStream_t stream) {
    const float* x   = (const float*)d_in[0];
    const int*   ei  = (const int*)d_in[1];
    const float* W1  = (const float*)d_in[2];
    const float* b1  = (const float*)d_in[3];
    const float* W2  = (const float*)d_in[4];
    const float* b2  = (const float*)d_in[5];
    const float* W3  = (const float*)d_in[6];
    const float* b3  = (const float*)d_in[7];
    const float* Wr1 = (const float*)d_in[8];
    const float* br1 = (const float*)d_in[9];
    const float* Wr2 = (const float*)d_in[10];
    const float* br2 = (const float*)d_in[11];
    float* out = (float*)d_out;

    const int N = NNODES;
    const int E = in_sizes[1] / 2;
    const int* srcp = ei;      // edge_index[0]
    const int* dstp = ei + E;  // edge_index[1]

    // workspace layout (~77 MB)
    double* pooled    = (double*)d_ws;                       // 8 doubles
    unsigned int* t1  = (unsigned int*)(pooled + HID);       // N x 4B (2MB)
    uint2* t2         = (uint2*)(t1 + N);                    // N x 8B (4MB)
    uint2* t3         = t2 + N;                              // N x 8B (4MB)
    int* gbinhist     = (int*)(t3 + N);                      // NBIN
    int* binexcl      = gbinhist + NBIN;                     // NBIN
    int* bsum         = binexcl + NBIN;                      // 1024
    int* ptr_bins     = bsum + 1024;                         // NBIN+1
    int* gcursor      = ptr_bins + NBIN + 1;                 // NBIN
    int* ptr          = gcursor + NBIN;                      // N+1
    int* ssrc         = ptr + N + 1;                         // E (64MB)

    hipMemsetAsync(gbinhist, 0, NBIN * sizeof(int), stream);
    hipMemsetAsync(pooled, 0, HID * sizeof(double), stream);

    const int BLK = 256;

    // CSR build
    binhist_kernel<<<128, 1024, 0, stream>>>(dstp, E, gbinhist);
    scan1_kernel<<<1, SCAN_BLK, 0, stream>>>(gbinhist, binexcl, bsum, NBIN);
    scan2_kernel<<<1, SCAN_BLK, 0, stream>>>(bsum, 1);
    scan3b_kernel<<<(NBIN + BLK - 1) / BLK, BLK, 0, stream>>>(binexcl, bsum, ptr_bins, gcursor, E);
    binscatter_kernel<<<SGRID, 1024, 0, stream>>>(srcp, dstp, E, gcursor, ssrc);
    binsort_kernel<<<NBIN, 512, 0, stream>>>(ptr_bins, ssrc, ptr, x, t1, N, E);

    // 3 gather passes, thread-per-node, grid-limited for L2 table residency
    agg1_kernel<<<AGRID, ABLK, 0, stream>>>(t1, ptr, ssrc, W1, b1, W2, t2, N);
    agg2_kernel<<<AGRID, ABLK, 0, stream>>>(t2, ptr, ssrc, b2, W3, t3, N);
    agg3_kernel<<<AGRID, ABLK, 0, stream>>>(t3, ptr, ssrc, b3, pooled, N);

    head_kernel<<<1, 64, 0, stream>>>(pooled, Wr1, br1, Wr2, br2, out, N);
}